// Round 10
// baseline (448.277 us; speedup 1.0000x reference)
//
#include <hip/hip_runtime.h>
#include <hip/hip_cooperative_groups.h>

// ErosionLayer: B=16, W=512, ITERS=10, fp32. PASSING numeric recipe
// (r5/r6/r8/r9, absmax 0.02734375): XLA-style greedy FMA via explicit fmaf()
// at exact sites, contract(off) elsewhere, correctly-rounded fp32 div/sqrt.
// DO NOT change op order or fusion sites.
//
// r10: LDS-tile megakernel. r9 was dependent-load-latency-bound (VALU 30%,
// HBM 10%, VGPR 64 -> serialized gather chains). Gather window is provably
// [c-1,c+2]x[r-1,r+2] (|fdx|,|fdy| <= 1), so each block owns a 16-row slice
// of one image with a 19x512 LDS tile (38.9 KB, halo rows 0/17/18).
// 512 blocks x 512 thr (thread = column, 16 rows each), launch_bounds(512,4):
// 2 blocks/CU, 32 waves/CU. Own rows persist in LDS across steps; only 3 halo
// rows reload from global after grid.sync(). s/w/v in registers.
#pragma clang fp contract(off)

namespace cg = cooperative_groups;

constexpr int WW    = 512;
constexpr int NPIX  = WW * WW;       // 2^18
constexpr int NTOT  = 16 * NPIX;     // 4194304
constexpr int ROWS  = 16;            // rows per block
constexpr int MTHR  = 512;           // mega block size (one thread per column)
constexpr int NBLK  = NTOT / (MTHR * ROWS);   // 512
constexpr int TROWS = ROWS + 3;      // tile rows: 1 top halo + 16 own + 2 bottom halo

// ---------------------------------------------------------------- shared math
// FROZEN r5/r6 per-cell step (global-pointer version, used by fallback path).
__device__ __forceinline__ void cell_step(
    const float* __restrict__ tb, int rem, int r, int c, float t_c,
    float rain_v, float gno_v,
    float rr, float evapr, float minhd, float heps, float gravr, float sccr,
    float diss, float depo,
    float& s_io, float& w_io, float& v_io, float& t_out, bool fin)
{
    #pragma clang fp contract(off)
    const float CELLW = 0.390625f;

    float w = fmaf(rr, rain_v, w_io);

    float dx, dy;
    if      (r == 0)      dx = 0.5f * fmaf(t_c, 1.1f, -t_c);
    else if (r == WW - 1) dx = 0.5f * fmaf(t_c, 0.9f, -t_c);
    else                  dx = 0.5f * (tb[rem + WW] - tb[rem - WW]);
    if      (c == 0)      dy = 0.5f * fmaf(t_c, 1.1f, -t_c);
    else if (c == WW - 1) dy = 0.5f * fmaf(t_c, 0.9f, -t_c);
    else                  dy = 0.5f * (tb[rem + 1] - tb[rem - 1]);

    float mag = sqrtf(fmaf(dx, dx, dy * dy) + 1e-11f);
    float rX  = gno_v;
    float rY  = sqrtf(fmaf(-rX, rX, 1.0f));
    float factor = fmaxf(1e-10f - mag, 0.0f);
    float den = mag + factor;
    float fdx = fmaf(factor, rX, dx) / den;
    float fdy = fmaf(factor, rY, dy) / den;

    float fx  = (float)c + (-fdx);
    float fy  = (float)r + (-fdy);
    float x0f = floorf(fx), y0f = floorf(fy);
    float wx1 = fx - x0f;
    float wy1 = fy - y0f;
    int x0 = (int)x0f, y0 = (int)y0f;
    int x1 = x0 + 1,   y1 = y0 + 1;

    bool vx0 = (x0 >= 0) & (x0 < WW);
    bool vx1 = (x1 >= 0) & (x1 < WW);
    bool vy0 = (y0 >= 0) & (y0 < WW);
    bool vy1 = (y1 >= 0) & (y1 < WW);
    int x0c = min(max(x0, 0), WW - 1), x1c = min(max(x1, 0), WW - 1);
    int y0c = min(max(y0, 0), WW - 1), y1c = min(max(y1, 0), WW - 1);

    float g00 = (vx0 && vy0) ? (tb[y0c * WW + x0c] - 1.0f) : 0.0f;
    float g10 = (vx1 && vy0) ? (tb[y0c * WW + x1c] - 1.0f) : 0.0f;
    float g01 = (vx0 && vy1) ? (tb[y1c * WW + x0c] - 1.0f) : 0.0f;
    float g11 = (vx1 && vy1) ? (tb[y1c * WW + x1c] - 1.0f) : 0.0f;

    float wx0 = 1.0f - wx1;
    float wy0 = 1.0f - wy1;
    float rowA = fmaf(wx0, g00, wx1 * g10);
    float rowB = fmaf(wx0, g01, wx1 * g11);
    float bil  = fmaf(wy0, rowA, wy1 * rowB);
    float neighbor = bil + 1.0f;

    float hd = t_c - neighbor;

    float v = v_io;
    float s = s_io;

    float hds  = ((hd - heps) > 0.0f) ? 1.0f : 0.0f;
    float nhd  = hds * fmaxf(hd, minhd);
    float q1 = nhd / CELLW;
    float q2 = q1 * v;
    float q3 = q2 * w;
    float sdiff = fmaf(-q3, sccr, s);
    float ftb   = (hd < 0.0f) ? 1.0f : 0.0f;
    float first = fminf(fmaxf(-hd, 0.0f), s);
    float ra = fmaxf(sdiff * depo, 0.0f);
    float rb = fmaxf((-sdiff) * diss, 0.0f);
    float deparg = fmaf(1.0f - ftb, ra - rb, first);
    float dep    = fmaxf(-fmaxf(hd, 0.0f), deparg);

    float s_new = s - dep;
    float t_new = t_c + dep;

    float rn = fmaxf(-fdy, 0.0f);
    float rm = fmaxf(1.0f - fabsf(fdy), 0.0f);
    float rp = fmaxf(fdy, 0.0f);

    float s1 = (c == WW - 1) ? 0.0f : rn * s_new;
    float s3 = (c == 0)      ? 0.0f : rp * s_new;
    s_io = fmaf(rm, s_new, s1) + s3;

    float w1 = (c == WW - 1) ? 0.0f : rn * w;
    float w3 = (c == 0)      ? 0.0f : rp * w;
    float wd = fmaf(rm, w, w1) + w3;
    w_io = wd * (1.0f - evapr);

    v_io = (gravr * hd) / CELLW;

    if (fin) {
        float aa = fmaf(-t_new, 2.0f, 1.0f);
        float bq = 1.0f + aa;
        t_out = fmaxf(bq, 0.0f) - 1.0f;
    } else {
        t_out = t_new;
    }
}

// ---------------------------------------------------------------- coop path
struct Args {
    const float* in_terr;
    float*       T0;      // d_out
    float*       T1;      // ws
    const float* rain;    // (10, W, W)
    const float* gno;     // (10, W, W)
    const float* p_rr; const float* p_evap; const float* p_minhd;
    const float* p_heps; const float* p_grav; const float* p_scc;
    const float* p_diss; const float* p_depo;
};

__global__ __launch_bounds__(MTHR, 4) void erosion_mega(Args a)
{
    #pragma clang fp contract(off)
    const float CELLW = 0.390625f;
    __shared__ float tile[TROWS * WW];     // 19 x 512 = 38912 B

    cg::grid_group grid = cg::this_grid();

    const int t    = threadIdx.x;          // column
    const int blk  = blockIdx.x;
    const int img  = blk >> 5;             // 32 slices per image
    const int row0 = (blk & 31) << 4;      // first owned row
    const int imgbase = img << 18;

    float rr    = fmaxf(a.p_rr[0], 0.0f);
    float evapr = fmaxf(a.p_evap[0], 0.0f);
    float minhd = a.p_minhd[0];
    float heps  = a.p_heps[0];
    float gravr = fmaxf(a.p_grav[0], 0.0f);
    float sccr  = fmaxf(a.p_scc[0], 0.0f);
    float diss  = a.p_diss[0];
    float depo  = a.p_depo[0];

    float sA[ROWS], wA[ROWS], vA[ROWS], tN[ROWS];

    // init: terrain into global T0 AND own tile rows (rows k -> tile row k+1)
    #pragma unroll
    for (int k = 0; k < ROWS; ++k) {
        int gidx = imgbase + (row0 + k) * WW + t;
        float t0 = (1.0f - a.in_terr[gidx]) / 2.0f;
        a.T0[gidx] = t0;
        tile[(k + 1) * WW + t] = t0;
        sA[k] = 0.0f; wA[k] = 0.0f; vA[k] = 0.0f;
    }
    grid.sync();
    // initial halo rows from T0: global rows row0-1, row0+16, row0+17
    {
        int g0 = row0 - 1, g1 = row0 + ROWS, g2 = row0 + ROWS + 1;
        if (g0 >= 0) tile[0 * WW + t]           = a.T0[imgbase + g0 * WW + t];
        if (g1 < WW) tile[(ROWS + 1) * WW + t]  = a.T0[imgbase + g1 * WW + t];
        if (g2 < WW) tile[(ROWS + 2) * WW + t]  = a.T0[imgbase + g2 * WW + t];
    }
    __syncthreads();

    #pragma unroll 1
    for (int it = 0; it < 10; ++it) {
        float*       tout = (it & 1) ? a.T0 : a.T1;
        const float* rain = a.rain + it * NPIX;
        const float* gno  = a.gno  + it * NPIX;
        const bool   fin  = (it == 9);

        // ---- phase A: compute all 16 cells from LDS tile ----
        #pragma unroll
        for (int k = 0; k < ROWS; ++k) {
            const int r    = row0 + k;
            const int c    = t;
            const int trow = k + 1;
            const int rem  = r * WW + c;

            float t_c = tile[trow * WW + c];

            float w = fmaf(rr, rain[rem], wA[k]);

            float dx, dy;
            if      (r == 0)      dx = 0.5f * fmaf(t_c, 1.1f, -t_c);
            else if (r == WW - 1) dx = 0.5f * fmaf(t_c, 0.9f, -t_c);
            else dx = 0.5f * (tile[(trow + 1) * WW + c] - tile[(trow - 1) * WW + c]);
            if      (c == 0)      dy = 0.5f * fmaf(t_c, 1.1f, -t_c);
            else if (c == WW - 1) dy = 0.5f * fmaf(t_c, 0.9f, -t_c);
            else dy = 0.5f * (tile[trow * WW + c + 1] - tile[trow * WW + c - 1]);

            float mag = sqrtf(fmaf(dx, dx, dy * dy) + 1e-11f);
            float rX  = gno[rem];
            float rY  = sqrtf(fmaf(-rX, rX, 1.0f));
            float factor = fmaxf(1e-10f - mag, 0.0f);
            float den = mag + factor;
            float fdx = fmaf(factor, rX, dx) / den;   // |fdx| <= 1
            float fdy = fmaf(factor, rY, dy) / den;   // |fdy| <= 1

            float fx  = (float)c + (-fdx);
            float fy  = (float)r + (-fdy);
            float x0f = floorf(fx), y0f = floorf(fy);
            float wx1 = fx - x0f;
            float wy1 = fy - y0f;
            int x0 = (int)x0f, y0 = (int)y0f;
            int x1 = x0 + 1,   y1 = y0 + 1;

            bool vx0 = (x0 >= 0) & (x0 < WW);
            bool vx1 = (x1 >= 0) & (x1 < WW);
            bool vy0 = (y0 >= 0) & (y0 < WW);
            bool vy1 = (y1 >= 0) & (y1 < WW);
            int x0c = min(max(x0, 0), WW - 1), x1c = min(max(x1, 0), WW - 1);
            int y0c = min(max(y0, 0), WW - 1), y1c = min(max(y1, 0), WW - 1);
            // tile rows for gather: y in [r-1, r+2] -> ty = y - (row0-1) in [0,18]
            int ty0 = y0c - row0 + 1;
            int ty1 = y1c - row0 + 1;

            float g00 = (vx0 && vy0) ? (tile[ty0 * WW + x0c] - 1.0f) : 0.0f;
            float g10 = (vx1 && vy0) ? (tile[ty0 * WW + x1c] - 1.0f) : 0.0f;
            float g01 = (vx0 && vy1) ? (tile[ty1 * WW + x0c] - 1.0f) : 0.0f;
            float g11 = (vx1 && vy1) ? (tile[ty1 * WW + x1c] - 1.0f) : 0.0f;

            float wx0 = 1.0f - wx1;
            float wy0 = 1.0f - wy1;
            float rowA = fmaf(wx0, g00, wx1 * g10);
            float rowB = fmaf(wx0, g01, wx1 * g11);
            float bil  = fmaf(wy0, rowA, wy1 * rowB);
            float neighbor = bil + 1.0f;

            float hd = t_c - neighbor;

            float v = vA[k];
            float s = sA[k];

            float hds  = ((hd - heps) > 0.0f) ? 1.0f : 0.0f;
            float nhd  = hds * fmaxf(hd, minhd);
            float q1 = nhd / CELLW;
            float q2 = q1 * v;
            float q3 = q2 * w;
            float sdiff = fmaf(-q3, sccr, s);
            float ftb   = (hd < 0.0f) ? 1.0f : 0.0f;
            float first = fminf(fmaxf(-hd, 0.0f), s);
            float ra = fmaxf(sdiff * depo, 0.0f);
            float rb = fmaxf((-sdiff) * diss, 0.0f);
            float deparg = fmaf(1.0f - ftb, ra - rb, first);
            float dep    = fmaxf(-fmaxf(hd, 0.0f), deparg);

            float s_new = s - dep;
            float t_new = t_c + dep;

            float rn = fmaxf(-fdy, 0.0f);
            float rm = fmaxf(1.0f - fabsf(fdy), 0.0f);
            float rp = fmaxf(fdy, 0.0f);

            float s1 = (c == WW - 1) ? 0.0f : rn * s_new;
            float s3 = (c == 0)      ? 0.0f : rp * s_new;
            sA[k] = fmaf(rm, s_new, s1) + s3;

            float w1 = (c == WW - 1) ? 0.0f : rn * w;
            float w3 = (c == 0)      ? 0.0f : rp * w;
            float wd = fmaf(rm, w, w1) + w3;
            wA[k] = wd * (1.0f - evapr);

            vA[k] = (gravr * hd) / CELLW;

            tN[k] = t_new;
        }

        __syncthreads();   // all tile reads done before rewrites

        // ---- phase B: commit t_new to tile (own rows) + global ----
        #pragma unroll
        for (int k = 0; k < ROWS; ++k) {
            int gidx = imgbase + (row0 + k) * WW + t;
            float tv = tN[k];
            if (fin) {
                float aa = fmaf(-tv, 2.0f, 1.0f);
                float bq = 1.0f + aa;
                tout[gidx] = fmaxf(bq, 0.0f) - 1.0f;
            } else {
                tout[gidx] = tv;
                tile[(k + 1) * WW + t] = tv;
            }
        }

        if (!fin) {
            grid.sync();
            int g0 = row0 - 1, g1 = row0 + ROWS, g2 = row0 + ROWS + 1;
            if (g0 >= 0) tile[0 * WW + t]          = tout[imgbase + g0 * WW + t];
            if (g1 < WW) tile[(ROWS + 1) * WW + t] = tout[imgbase + g1 * WW + t];
            if (g2 < WW) tile[(ROWS + 2) * WW + t] = tout[imgbase + g2 * WW + t];
            __syncthreads();
        }
    }
}

// ---------------------------------------------------------------- fallback (r6)
__global__ __launch_bounds__(256) void erosion_init(
    const float* __restrict__ in, float* __restrict__ terr,
    float* __restrict__ sed, float* __restrict__ wat, float* __restrict__ vel)
{
    #pragma clang fp contract(off)
    int idx = blockIdx.x * 256 + threadIdx.x;
    terr[idx] = (1.0f - in[idx]) / 2.0f;
    sed[idx] = 0.0f;
    wat[idx] = 0.0f;
    vel[idx] = 0.0f;
}

__global__ __launch_bounds__(256) void erosion_step(
    const float* __restrict__ terr_in, float* __restrict__ terr_out,
    float* __restrict__ sed, float* __restrict__ wat, float* __restrict__ vel,
    const float* __restrict__ rain, const float* __restrict__ gnoise,
    const float* __restrict__ s_rain_rate, const float* __restrict__ s_evap,
    const float* __restrict__ s_minhd, const float* __restrict__ s_heps,
    const float* __restrict__ s_grav, const float* __restrict__ s_scc,
    const float* __restrict__ s_diss, const float* __restrict__ s_depo,
    int final_flag)
{
    #pragma clang fp contract(off)
    int idx = blockIdx.x * 256 + threadIdx.x;
    int rem = idx & (NPIX - 1);
    int r   = rem >> 9;
    int c   = rem & (WW - 1);
    const float* tb = terr_in + (long)(idx - rem);

    float rr    = fmaxf(s_rain_rate[0], 0.0f);
    float evapr = fmaxf(s_evap[0], 0.0f);
    float minhd = s_minhd[0];
    float heps  = s_heps[0];
    float gravr = fmaxf(s_grav[0], 0.0f);
    float sccr  = fmaxf(s_scc[0], 0.0f);
    float diss  = s_diss[0];
    float depo  = s_depo[0];

    float s = sed[idx], w0 = wat[idx], v = vel[idx];
    float t_res;
    cell_step(tb, rem, r, c, tb[rem], rain[rem], gnoise[rem],
              rr, evapr, minhd, heps, gravr, sccr, diss, depo,
              s, w0, v, t_res, final_flag != 0);
    sed[idx] = s; wat[idx] = w0; vel[idx] = v;
    terr_out[idx] = t_res;
}

// ---------------------------------------------------------------- launch
extern "C" void kernel_launch(void* const* d_in, const int* in_sizes, int n_in,
                              void* d_out, int out_size, void* d_ws, size_t ws_size,
                              hipStream_t stream) {
    Args a;
    a.in_terr = (const float*)d_in[0];
    a.rain    = (const float*)d_in[1];
    a.gno     = (const float*)d_in[2];
    a.p_rr    = (const float*)d_in[3];
    a.p_evap  = (const float*)d_in[4];
    a.p_minhd = (const float*)d_in[5];
    a.p_heps  = (const float*)d_in[6];
    a.p_grav  = (const float*)d_in[7];
    a.p_scc   = (const float*)d_in[8];
    a.p_diss  = (const float*)d_in[9];
    a.p_depo  = (const float*)d_in[10];
    a.T0      = (float*)d_out;
    a.T1      = (float*)d_ws;

    // Host-side routing (capture-legal, deterministic).
    bool coop_ok = false;
    int dev = 0;
    (void)hipGetDevice(&dev);
    int numCU = 0;
    if (hipDeviceGetAttribute(&numCU, hipDeviceAttributeMultiprocessorCount, dev) == hipSuccess) {
        int perCU = 0;
        if (hipOccupancyMaxActiveBlocksPerMultiprocessor(&perCU, (const void*)erosion_mega,
                                                         MTHR, 0) == hipSuccess) {
            coop_ok = ((long)perCU * numCU >= NBLK);
        }
    }

    if (coop_ok) {
        void* kargs[] = { &a };
        if (hipLaunchCooperativeKernel((void*)erosion_mega, dim3(NBLK), dim3(MTHR),
                                       kargs, 0, stream) == hipSuccess)
            return;
    }

    // Fallback: proven r6 multi-kernel sequence (442 us, absmax 0.0273).
    float* T0  = (float*)d_out;
    float* ws  = (float*)d_ws;
    float* T1  = ws;
    float* sed = ws + (size_t)NTOT;
    float* wat = ws + (size_t)2 * NTOT;
    float* vel = ws + (size_t)3 * NTOT;

    dim3 grid(NTOT / 256), block(256);
    erosion_init<<<grid, block, 0, stream>>>(a.in_terr, T0, sed, wat, vel);
    for (int it = 0; it < 10; ++it) {
        const float* tin  = (it & 1) ? T1 : T0;
        float*       tout = (it & 1) ? T0 : T1;
        erosion_step<<<grid, block, 0, stream>>>(
            tin, tout, sed, wat, vel,
            a.rain + (size_t)it * NPIX, a.gno + (size_t)it * NPIX,
            a.p_rr, a.p_evap, a.p_minhd, a.p_heps, a.p_grav, a.p_scc,
            a.p_diss, a.p_depo, (it == 9) ? 1 : 0);
    }
}